// Round 3
// baseline (550.888 us; speedup 1.0000x reference)
//
#include <hip/hip_runtime.h>

#define GAMMA 0.99f
#define BETA  0.01f
// Problem shape (fixed): B=65536, T=128, A=8.
//
// R3: persistent steady-state pipeline probe. R0 (reg loads, 24 waves/CU) and
// R2 (LDS-DMA, 12 waves/CU) both measured the same 3.5 TB/s effective read
// rate despite >10x the in-flight bytes needed for 6.3 TB/s -> either the read
// path caps at ~14 B/cy/CU, or the burst-issue/full-drain/block-churn pattern
// leaves the queues empty between bursts. This kernel removes the second
// explanation: 512 blocks (2/CU, fully resident, zero churn), each wave
// streams 32 rows through double-buffered LDS staging with counted
// s_waitcnt vmcnt(14) (never 0 in the loop) so ~14-28 requests stay in
// flight per wave continuously. ALL inputs go through global_load_lds, so
// the compiler has no vmem dataflow and cannot insert draining waits.
//
// Wave-buffer layout (floats):
//   [0,1024)    lp row (natural order)
//   [1024,2048) ent row
//   [2048,2176) values row (128)
//   [2176,2304) rewards row (128)
//   [2304,2368) last_value dup x64
//   [2368,2432) terminal dup x64
// Stage = 14 vmem ops: 4x16B lp + 4x16B ent + 2x4B v + 2x4B r + 1x4B lv + 1x4B tm.
// Ledger: needed stage is always >=14 ops older than its wait -> vmcnt(14) safe.

typedef const __attribute__((address_space(1))) void GVoid;
typedef __attribute__((address_space(3))) void LVoid;

#define BUF_FLOATS 2432
#define ROWS_PER_WAVE 32

#define WAITV(N) do { \
    asm volatile("s_waitcnt vmcnt(" #N ")" ::: "memory"); \
    __builtin_amdgcn_sched_barrier(0); \
} while (0)

__global__ __launch_bounds__(256, 2) void a3c_loss_kernel(
    const float* __restrict__ values,        // [B,128]
    const float* __restrict__ last_value,    // [B]
    const float* __restrict__ rewards,       // [B,128]
    const float* __restrict__ log_probs,     // [B,128,8]
    const float* __restrict__ entropies,     // [B,128,8]
    const int*   __restrict__ terminal_mask, // [B]
    float* __restrict__ out,                 // [B,2] = (actor, critic)
    int B)
{
    __shared__ float lds[4][2][BUF_FLOATS];  // 77,824 B/block -> 2 blocks/CU

    const int wave = threadIdx.x >> 6;
    const int lane = threadIdx.x & 63;
    const int wid  = blockIdx.x * 4 + wave;  // global wave id
    const int r0   = wid * ROWS_PER_WAVE;
    if (r0 >= B) return;

    float* const buf0 = &lds[wave][0][0];
    float* const buf1 = &lds[wave][1][0];

    // ---- stage one row into a wave-private LDS buffer: exactly 14 vmem ops ----
    auto stage = [&](float* buf, int row) {
        row = (row < B) ? row : (B - 1);     // uniform op count even at edges
        const size_t rb = (size_t)row;
        const float4* lp4 = reinterpret_cast<const float4*>(log_probs + rb * 1024) + lane;
        const float4* en4 = reinterpret_cast<const float4*>(entropies + rb * 1024) + lane;
        #pragma unroll
        for (int k = 0; k < 4; ++k)
            __builtin_amdgcn_global_load_lds((GVoid*)(lp4 + 64 * k),
                                             (LVoid*)(buf + 256 * k), 16, 0, 0);
        #pragma unroll
        for (int k = 0; k < 4; ++k)
            __builtin_amdgcn_global_load_lds((GVoid*)(en4 + 64 * k),
                                             (LVoid*)(buf + 1024 + 256 * k), 16, 0, 0);
        const float* vp = values  + rb * 128 + lane;
        const float* rp = rewards + rb * 128 + lane;
        __builtin_amdgcn_global_load_lds((GVoid*)(vp     ), (LVoid*)(buf + 2048     ), 4, 0, 0);
        __builtin_amdgcn_global_load_lds((GVoid*)(vp + 64), (LVoid*)(buf + 2048 + 64), 4, 0, 0);
        __builtin_amdgcn_global_load_lds((GVoid*)(rp     ), (LVoid*)(buf + 2176     ), 4, 0, 0);
        __builtin_amdgcn_global_load_lds((GVoid*)(rp + 64), (LVoid*)(buf + 2176 + 64), 4, 0, 0);
        __builtin_amdgcn_global_load_lds((GVoid*)(last_value    + rb), (LVoid*)(buf + 2304), 4, 0, 0);
        __builtin_amdgcn_global_load_lds((GVoid*)(terminal_mask + rb), (LVoid*)(buf + 2368), 4, 0, 0);
        __builtin_amdgcn_sched_barrier(0);
    };

    // ---- consume a staged row (caller has already done the vmcnt wait) ----
    auto process = [&](const float* buf, int row) {
        const float2 v2 = reinterpret_cast<const float2*>(buf + 2048)[lane];
        const float2 r2 = reinterpret_cast<const float2*>(buf + 2176)[lane];
        const float  lv = buf[2304 + lane];
        const int    tm = reinterpret_cast<const int*>(buf)[2368 + lane];

        const float v0 = v2.x, v1 = v2.y;
        const float r0v = r2.x, r1v = r2.y;

        const float R0 = (tm != 0) ? 0.0f : lv;

        // v_next at t1 = v[2l+2] = lane (l+1)'s v0; lane 63 -> R0
        float vnext1 = __shfl_down(v0, 1, 64);
        if (lane == 63) vnext1 = R0;
        const float delta1 = r1v + GAMMA * vnext1 - v1;
        const float delta0 = r0v + GAMMA * v1    - v0;

        // per-lane affine segment maps (descending t: t1 then t0)
        float m  = GAMMA * GAMMA;
        float cR = fmaf(GAMMA, r1v, r0v);
        float cG = fmaf(GAMMA, delta1, delta0);

        // inclusive suffix scan of map composition
        #pragma unroll
        for (int d = 1; d < 64; d <<= 1) {
            const float om  = __shfl_down(m,  d, 64);
            const float ocR = __shfl_down(cR, d, 64);
            const float ocG = __shfl_down(cG, d, 64);
            if (lane + d < 64) {
                cR = fmaf(m, ocR, cR);
                cG = fmaf(m, ocG, cG);
                m  = m * om;
            }
        }
        float pm  = __shfl_down(m,  1, 64);
        float pcR = __shfl_down(cR, 1, 64);
        float pcG = __shfl_down(cG, 1, 64);
        if (lane == 63) { pm = 1.0f; pcR = 0.0f; pcG = 0.0f; }

        const float Rin = fmaf(pm, R0, pcR);
        const float gin = pcG;

        const float R1   = fmaf(GAMMA, Rin, r1v);
        const float Rt0  = fmaf(GAMMA, R1,  r0v);
        const float adv1 = R1  - v1;
        const float adv0 = Rt0 - v0;
        float critic = 0.5f * (adv1 * adv1 + adv0 * adv0);

        const float g1 = fmaf(GAMMA, gin, delta1);
        const float g0 = fmaf(GAMMA, g1,  delta0);

        // redistribute gae to the coalesced-lp layout
        const int par = (lane >> 1) & 1;
        const int hb  = lane >> 2;
        const float gA0 = __shfl(g0, hb,      64), gB0 = __shfl(g1, hb,      64);
        const float gA1 = __shfl(g0, hb + 16, 64), gB1 = __shfl(g1, hb + 16, 64);
        const float gA2 = __shfl(g0, hb + 32, 64), gB2 = __shfl(g1, hb + 32, 64);
        const float gA3 = __shfl(g0, hb + 48, 64), gB3 = __shfl(g1, hb + 48, 64);
        const float gk0 = par ? gB0 : gA0;
        const float gk1 = par ? gB1 : gA1;
        const float gk2 = par ? gB2 : gA2;
        const float gk3 = par ? gB3 : gA3;

        const float4* lpL = reinterpret_cast<const float4*>(buf);
        const float4* enL = reinterpret_cast<const float4*>(buf + 1024);
        const float4 L0 = lpL[lane      ];
        const float4 L1 = lpL[lane +  64];
        const float4 L2 = lpL[lane + 128];
        const float4 L3 = lpL[lane + 192];
        const float4 E0 = enL[lane      ];
        const float4 E1 = enL[lane +  64];
        const float4 E2 = enL[lane + 128];
        const float4 E3 = enL[lane + 192];

        const float sL0 = (L0.x + L0.y) + (L0.z + L0.w);
        const float sL1 = (L1.x + L1.y) + (L1.z + L1.w);
        const float sL2 = (L2.x + L2.y) + (L2.z + L2.w);
        const float sL3 = (L3.x + L3.y) + (L3.z + L3.w);
        float actor = -(sL0 * gk0 + sL1 * gk1 + sL2 * gk2 + sL3 * gk3);

        const float esum = ((E0.x + E0.y) + (E0.z + E0.w)) + ((E1.x + E1.y) + (E1.z + E1.w))
                         + ((E2.x + E2.y) + (E2.z + E2.w)) + ((E3.x + E3.y) + (E3.z + E3.w));
        actor = fmaf(-BETA, esum, actor);

        #pragma unroll
        for (int d = 32; d >= 1; d >>= 1) {
            actor  += __shfl_down(actor,  d, 64);
            critic += __shfl_down(critic, d, 64);
        }

        if (lane == 0 && row < B) {
            reinterpret_cast<float2*>(out)[row] = make_float2(actor, critic);
        }
        __builtin_amdgcn_sched_barrier(0);
    };

    // ---- steady-state double-buffered pipeline over 32 rows ----
    stage(buf0, r0);
    #pragma unroll 1
    for (int i = 0; i < ROWS_PER_WAVE - 2; i += 2) {
        stage(buf1, r0 + i + 1);
        WAITV(14);                    // row i staged; next 14 ops stay in flight
        process(buf0, r0 + i);
        stage(buf0, r0 + i + 2);
        WAITV(14);                    // row i+1 staged
        process(buf1, r0 + i + 1);
    }
    stage(buf1, r0 + ROWS_PER_WAVE - 1);
    WAITV(14);                        // row 30 staged
    process(buf0, r0 + ROWS_PER_WAVE - 2);
    WAITV(0);                         // final drain
    process(buf1, r0 + ROWS_PER_WAVE - 1);
}

extern "C" void kernel_launch(void* const* d_in, const int* in_sizes, int n_in,
                              void* d_out, int out_size, void* d_ws, size_t ws_size,
                              hipStream_t stream) {
    const float* values      = (const float*)d_in[0];
    const float* last_value  = (const float*)d_in[1];
    const float* rewards     = (const float*)d_in[2];
    const float* log_probs   = (const float*)d_in[3];
    const float* entropies   = (const float*)d_in[4];
    const int*   terminal    = (const int*)d_in[5];
    float* out = (float*)d_out;

    const int B = in_sizes[1];                      // 65536
    const int blocks = (B + 127) / 128;             // 512: 4 waves x 32 rows per block
    a3c_loss_kernel<<<blocks, 256, 0, stream>>>(
        values, last_value, rewards, log_probs, entropies, terminal, out, B);
}

// Round 4
// 533.352 us; speedup vs baseline: 1.0329x; 1.0329x over previous
//
#include <hip/hip_runtime.h>

#define GAMMA 0.99f
#define BETA  0.01f
// Problem shape (fixed): B=65536, T=128, A=8.
// One 64-lane wave per batch row; lane l owns timesteps t0=2l, t1=2l+1 for the
// scan. lp/ent are loaded fully coalesced (lane l -> float4 index l+64k) and
// the gae weights are redistributed with shuffles after the scan.
//
// ROOFLINE NOTE (session R0-R3): this kernel runs at the read-path ceiling.
// Three structurally independent variants (burst VGPR loads @24 waves/CU;
// burst global_load_lds DMA @12 waves/CU; persistent double-buffered
// pipeline with counted s_waitcnt vmcnt(14)) all measure 163-178 us =
// 604.5 MB of mandatory reads at ~3.7 TB/s effective. Duration is invariant
// to occupancy (20-77%), in-flight bytes (~10x range), AND data source:
// rocprof replays with ~100% Infinity-Cache-served reads (hbm_bytes ~0.5 MB)
// take the same 162-169 us as 50%-HBM dispatches. The limiter is the common
// CU->L2->fabric read path (~463 GB/s/XCD ~= 256 B/fclk read port), not HBM
// BW, not latency/MLP, not compute (VALUBusy ~10%). Every byte is
// algorithmically required and already read as maximal 1024 B/wave
// coalesced dwordx4 -> no software lever remains. Keep this version: it is
// the fastest measured (162-169 us dispatch; simpler burst structure beats
// the persistent pipeline by ~8% on loop overhead).

__global__ __launch_bounds__(256, 6) void a3c_loss_kernel(
    const float* __restrict__ values,        // [B,128]
    const float* __restrict__ last_value,    // [B]
    const float* __restrict__ rewards,       // [B,128]
    const float* __restrict__ log_probs,     // [B,128,8]
    const float* __restrict__ entropies,     // [B,128,8]
    const int*   __restrict__ terminal_mask, // [B]
    float* __restrict__ out,                 // [B,2] = (actor, critic)
    int B)
{
    const int wave = threadIdx.x >> 6;
    const int lane = threadIdx.x & 63;
    const int b = blockIdx.x * 4 + wave;
    if (b >= B) return;

    // ---- issue scan-critical loads first ----
    const float2 v2 = reinterpret_cast<const float2*>(values  + (size_t)b * 128)[lane];
    const float2 r2 = reinterpret_cast<const float2*>(rewards + (size_t)b * 128)[lane];
    const float lv  = last_value[b];
    const int   tm  = terminal_mask[b];

    // ---- fully coalesced lp/ent loads: lane l reads float4 at l+64k ----
    const float4* lp4 = reinterpret_cast<const float4*>(log_probs + (size_t)b * 1024);
    const float4* en4 = reinterpret_cast<const float4*>(entropies + (size_t)b * 1024);
    const float4 L0 = lp4[lane      ];
    const float4 L1 = lp4[lane +  64];
    const float4 L2 = lp4[lane + 128];
    const float4 L3 = lp4[lane + 192];
    const float4 E0 = en4[lane      ];
    const float4 E1 = en4[lane +  64];
    const float4 E2 = en4[lane + 128];
    const float4 E3 = en4[lane + 192];

    const float v0 = v2.x, v1 = v2.y;
    const float r0 = r2.x, r1 = r2.y;

    // Bootstrap value (wave-uniform)
    const float R0 = (tm != 0) ? 0.0f : lv;

    // v_next at t1 = v[2l+2] = lane (l+1)'s v0; lane 63 -> R0
    float vnext1 = __shfl_down(v0, 1, 64);
    if (lane == 63) vnext1 = R0;
    const float delta1 = r1 + GAMMA * vnext1 - v1;
    const float delta0 = r0 + GAMMA * v1    - v0;   // v_next at t0 is v1 (local)

    // ---- per-lane affine segment maps (applied in descending t: t1 then t0) ----
    // R:   x -> gamma^2 * x + (gamma*r1 + r0)
    // gae: x -> gamma^2 * x + (gamma*delta1 + delta0)
    float m  = GAMMA * GAMMA;
    float cR = fmaf(GAMMA, r1, r0);
    float cG = fmaf(GAMMA, delta1, delta0);

    // Inclusive suffix scan of map composition: S_l = M_l o S_{l+1}
    #pragma unroll
    for (int d = 1; d < 64; d <<= 1) {
        const float om  = __shfl_down(m,  d, 64);
        const float ocR = __shfl_down(cR, d, 64);
        const float ocG = __shfl_down(cG, d, 64);
        if (lane + d < 64) {
            cR = fmaf(m, ocR, cR);
            cG = fmaf(m, ocG, cG);
            m  = m * om;
        }
    }
    // Exclusive suffix (incoming carry) = S_{l+1}; lane 63 gets identity
    float pm  = __shfl_down(m,  1, 64);
    float pcR = __shfl_down(cR, 1, 64);
    float pcG = __shfl_down(cG, 1, 64);
    if (lane == 63) { pm = 1.0f; pcR = 0.0f; pcG = 0.0f; }

    const float Rin = fmaf(pm, R0, pcR);   // R entering this lane's segment
    const float gin = pcG;                 // gae entering (gae starts at 0)

    // Evaluate the two local timesteps (t1 first, then t0)
    const float R1   = fmaf(GAMMA, Rin, r1);
    const float Rt0  = fmaf(GAMMA, R1,  r0);
    const float adv1 = R1  - v1;
    const float adv0 = Rt0 - v0;
    float critic = 0.5f * (adv1 * adv1 + adv0 * adv0);

    const float g1 = fmaf(GAMMA, gin, delta1);  // gae at t=2l+1
    const float g0 = fmaf(GAMMA, g1,  delta0);  // gae at t=2l

    // ---- redistribute gae to the coalesced-lp layout ----
    // float4 index j = lane + 64k covers t = j>>1, holder lane h = j>>2 =
    // (lane>>2)+16k, parity (t&1) = (lane>>1)&1 selects g0 (even t) vs g1.
    const int par = (lane >> 1) & 1;
    const int hb  = lane >> 2;
    float actor = 0.0f;
    {
        const int h0 = hb;
        const int h1 = hb + 16;
        const int h2 = hb + 32;
        const int h3 = hb + 48;
        const float gA0 = __shfl(g0, h0, 64), gB0 = __shfl(g1, h0, 64);
        const float gA1 = __shfl(g0, h1, 64), gB1 = __shfl(g1, h1, 64);
        const float gA2 = __shfl(g0, h2, 64), gB2 = __shfl(g1, h2, 64);
        const float gA3 = __shfl(g0, h3, 64), gB3 = __shfl(g1, h3, 64);
        const float gk0 = par ? gB0 : gA0;
        const float gk1 = par ? gB1 : gA1;
        const float gk2 = par ? gB2 : gA2;
        const float gk3 = par ? gB3 : gA3;
        const float sL0 = (L0.x + L0.y) + (L0.z + L0.w);
        const float sL1 = (L1.x + L1.y) + (L1.z + L1.w);
        const float sL2 = (L2.x + L2.y) + (L2.z + L2.w);
        const float sL3 = (L3.x + L3.y) + (L3.z + L3.w);
        actor = -(sL0 * gk0 + sL1 * gk1 + sL2 * gk2 + sL3 * gk3);
    }
    // Entropy: pure full-row sum, no redistribution needed.
    const float esum = ((E0.x + E0.y) + (E0.z + E0.w)) + ((E1.x + E1.y) + (E1.z + E1.w))
                     + ((E2.x + E2.y) + (E2.z + E2.w)) + ((E3.x + E3.y) + (E3.z + E3.w));
    actor = fmaf(-BETA, esum, actor);

    // ---- wave reduction over the 64 lanes ----
    #pragma unroll
    for (int d = 32; d >= 1; d >>= 1) {
        actor  += __shfl_down(actor,  d, 64);
        critic += __shfl_down(critic, d, 64);
    }

    if (lane == 0) {
        reinterpret_cast<float2*>(out)[b] = make_float2(actor, critic);
    }
}

extern "C" void kernel_launch(void* const* d_in, const int* in_sizes, int n_in,
                              void* d_out, int out_size, void* d_ws, size_t ws_size,
                              hipStream_t stream) {
    const float* values      = (const float*)d_in[0];
    const float* last_value  = (const float*)d_in[1];
    const float* rewards     = (const float*)d_in[2];
    const float* log_probs   = (const float*)d_in[3];
    const float* entropies   = (const float*)d_in[4];
    const int*   terminal    = (const int*)d_in[5];
    float* out = (float*)d_out;

    const int B = in_sizes[1];              // 65536
    const int blocks = (B + 3) / 4;         // 4 waves (batches) per 256-thread block

    a3c_loss_kernel<<<blocks, 256, 0, stream>>>(
        values, last_value, rewards, log_probs, entropies, terminal, out, B);
}